// Round 19
// baseline (372.998 us; speedup 1.0000x reference)
//
#include <hip/hip_runtime.h>

// 4D conv net, MI355X. S=30, B=2, ch 1->10->10->1, kernel 3^4, pad 1, ReLU.
// out = net(x,w) + net(x,w_swap), w_swap has (k1,k2)<->(k3,k4).
// R7-R17: 32x32x16 bf16 MFMA, XCD-chunk swizzle, B-table in LDS, rotate-A
// depth-1 prefetch, barrier-free per-wave epilogue. conv_k = 69.5 us.
// R22 (384): +fused prep. R23 (375): conv0ab/conv2ab branch merges
// (single out store kills RMW). R24/R25 (365): conv1ab z=8 merge + 4-buffer
// single-pass prep.
// R26: prep + conv0ab fused into ONE dispatch (prep0_k, 5442 blocks):
//  - blocks 0..41 build ft (read only by conv1ab/conv2ab, later dispatches)
//  - blocks 42..1841 zero HALO bytes of y1a/y1b/y2a/y2b
//  - blocks 1842..5441 run conv0 both branches, B-frags computed INLINE
//    from w1 (48 L2-hot loads/block) -> no ftL0 dependency; interior
//    writes are disjoint from halo writes -> race-free any order.
// 5 dispatches -> 3. conv1ab/conv2ab byte-identical controls.

static constexpr int S  = 30;
static constexpr long S4 = 810000;
static constexpr size_t PLANE = 32768;                  // 32*32*16*2 B
static constexpr size_t YBYTES = (size_t)1800 * PLANE;  // [b(2)][g1][g2]

typedef __bf16 bf16x8 __attribute__((ext_vector_type(8)));
typedef float  f32x16 __attribute__((ext_vector_type(16)));
typedef unsigned int  u32;
typedef unsigned short u16;

static __device__ __forceinline__ u16 f2bf(float f) {
    u32 u = __builtin_bit_cast(u32, f);
    return (u16)((u + 0x7fffu + ((u >> 16) & 1u)) >> 16);
}

// ---------------------------------------------------------------------------
// Shared device helpers.
static __device__ __forceinline__ void l0_frags(
    const float* __restrict__ x, int b, int h1, int w1i, int rbase,
    int m, int hl, uint4* F)
{
    int gof[9]; int gokm = 0;
#pragma unroll
    for (int k12 = 0; k12 < 9; ++k12) {
        const int g1 = h1 + k12 / 3 - 1, g2 = w1i + k12 % 3 - 1;
        gof[k12] = 0;
        if (g1 >= 0 && g1 < S && g2 >= 0 && g2 < S) {
            gof[k12] = (g1 * S + g2) * 900; gokm |= 1 << k12;
        }
    }
    const float* xb = x + (size_t)b * S4;
#pragma unroll
    for (int f = 0; f < 6; ++f) {
        const int hp = rbase + f;
        const bool rk = (hp >= 1 && hp <= 30 && m >= 1 && m <= 30);
        const int ro = (hp - 1) * 30 + (m - 1);
        u16 av[8];
#pragma unroll
        for (int j = 0; j < 8; ++j) av[j] = 0;
        if (hl == 0) {
#pragma unroll
            for (int j = 0; j < 8; ++j) {
                float v = 0.f;
                if (rk && ((gokm >> j) & 1)) v = xb[gof[j] + ro];
                av[j] = f2bf(v);
            }
        } else {
            float v = 0.f;
            if (rk && ((gokm >> 8) & 1)) v = xb[gof[8] + ro];
            av[0] = f2bf(v);
        }
        F[f] = make_uint4((u32)av[0] | ((u32)av[1] << 16),
                          (u32)av[2] | ((u32)av[3] << 16),
                          (u32)av[4] | ((u32)av[5] << 16),
                          (u32)av[6] | ((u32)av[7] << 16));
    }
}

// Inline L0 B-fragment: equals the ftL0 table entry [sw][k3][lane].
static __device__ __forceinline__ uint4 l0_bfrag(
    const float* __restrict__ w1, int sw, int k3, int n, int hl)
{
    u16 us[8];
#pragma unroll
    for (int j = 0; j < 8; ++j) us[j] = 0;
    if (n < 30) {
        const int k4 = (n < 10) ? 0 : ((n < 20) ? 1 : 2);
        const int co = n - 10 * k4;
#pragma unroll
        for (int j = 0; j < 8; ++j) {
            const int k12 = hl * 8 + j;
            if (k12 < 9) {
                const int k1 = k12 / 3, k2 = k12 % 3;
                const int i1 = sw ? k3 : k1, i2 = sw ? k4 : k2;
                const int i3 = sw ? k1 : k3, i4 = sw ? k2 : k4;
                const int widx = ((i1 * 3 + i2) * 3 + i3) * 3 + i4;
                us[j] = f2bf(w1[co * 81 + widx]);
            }
        }
    }
    return make_uint4((u32)us[0] | ((u32)us[1] << 16),
                      (u32)us[2] | ((u32)us[3] << 16),
                      (u32)us[4] | ((u32)us[5] << 16),
                      (u32)us[6] | ((u32)us[7] << 16));
}

static __device__ __forceinline__ void plane_epilogue(
    float* Ew, const f32x16* acc, const float* __restrict__ bias,
    void* __restrict__ outp, int b, int h1, int w1i, int rbase,
    int m, int hl, int lane, int wv)
{
    for (int r = 0; r < 4; ++r) {
        if (wv == 3 && r == 3) continue;
#pragma unroll
        for (int gq = 0; gq < 4; ++gq)
#pragma unroll
            for (int r4 = 0; r4 < 4; ++r4)
                Ew[m * 33 + 4 * hl + 8 * gq + r4] = acc[r][gq * 4 + r4];

        const int h2 = rbase + r;
        char* pl = (char*)outp + ((size_t)b * 900 + h1 * S + w1i) * PLANE
                   + (size_t)(h2 + 1) * 1024;
        const int t = lane >> 1, h8 = lane & 1;
        if (t < 30) {
            u32 wo[4];
#pragma unroll
            for (int p = 0; p < 4; ++p) {
                const int c0 = 8 * h8 + 2 * p, c1 = c0 + 1;
                float v0 = 0.f, v1 = 0.f;
                if (c0 < 10)
                    v0 = fmaxf(Ew[c0 * 33 + t] + Ew[(10 + c0) * 33 + t + 1]
                             + Ew[(20 + c0) * 33 + t + 2] + bias[c0], 0.f);
                if (c1 < 10)
                    v1 = fmaxf(Ew[c1 * 33 + t] + Ew[(10 + c1) * 33 + t + 1]
                             + Ew[(20 + c1) * 33 + t + 2] + bias[c1], 0.f);
                wo[p] = (u32)f2bf(v0) | ((u32)f2bf(v1) << 16);
            }
            *(uint4*)(pl + (t + 1) * 32 + h8 * 16) =
                make_uint4(wo[0], wo[1], wo[2], wo[3]);
        }
    }
}

// ---------------------------------------------------------------------------
// FUSED prep + conv0ab: 5442 blocks.
//  0..41     fragprep (writes ft; consumed by LATER dispatches only)
//  42..1841  zero halos of y1a/y1b/y2a/y2b (disjoint from conv0 interiors)
//  1842..5441 conv0 both branches, inline B-frags, write y1a/y1b interiors
__global__ __launch_bounds__(256, 2) void prep0_k(u32* __restrict__ ft,
    const float* __restrict__ w1, const float* __restrict__ w2,
    const float* __restrict__ w3, u16* __restrict__ y1a,
    u16* __restrict__ y1b, u16* __restrict__ y2a, u16* __restrict__ y2b,
    const float* __restrict__ x, const float* __restrict__ b1)
{
    __shared__ float E[4][1056];
    const int bid = blockIdx.x;
    const int tid = threadIdx.x;

    if (bid >= 1842) {                          // ---- conv0ab role ----
        const int wgid = bid - 1842;
        const int id2  = (wgid & 7) * 450 + (wgid >> 3);
        const int half = id2 & 1;
        int sp = id2 >> 1;
        const int w1i = sp % S; sp /= S;
        const int h1  = sp % S;
        const int b   = sp / S;
        const int lane = tid & 63, wv = tid >> 6;
        const int m = lane & 31, hl = lane >> 5;
        const int rbase = half * 15 + wv * 4;

        uint4 F[6];
        l0_frags(x, b, h1, w1i, rbase, m, hl, F);

        f32x16 acc[4];
        // branch 0
        {
            uint4 Bs[3];
#pragma unroll
            for (int ss = 0; ss < 3; ++ss) Bs[ss] = l0_bfrag(w1, 0, ss, m, hl);
#pragma unroll
            for (int r = 0; r < 4; ++r)
#pragma unroll
                for (int e = 0; e < 16; ++e) acc[r][e] = 0.f;
#pragma unroll
            for (int ss = 0; ss < 3; ++ss)
#pragma unroll
                for (int r = 0; r < 4; ++r)
                    acc[r] = __builtin_amdgcn_mfma_f32_32x32x16_bf16(
                        __builtin_bit_cast(bf16x8, F[r + ss]),
                        __builtin_bit_cast(bf16x8, Bs[ss]), acc[r], 0, 0, 0);
            plane_epilogue(E[wv], acc, b1, y1a, b, h1, w1i, rbase, m, hl, lane, wv);
        }
        // branch 1
        {
            uint4 Bs[3];
#pragma unroll
            for (int ss = 0; ss < 3; ++ss) Bs[ss] = l0_bfrag(w1, 1, ss, m, hl);
#pragma unroll
            for (int r = 0; r < 4; ++r)
#pragma unroll
                for (int e = 0; e < 16; ++e) acc[r][e] = 0.f;
#pragma unroll
            for (int ss = 0; ss < 3; ++ss)
#pragma unroll
                for (int r = 0; r < 4; ++r)
                    acc[r] = __builtin_amdgcn_mfma_f32_32x32x16_bf16(
                        __builtin_bit_cast(bf16x8, F[r + ss]),
                        __builtin_bit_cast(bf16x8, Bs[ss]), acc[r], 0, 0, 0);
            plane_epilogue(E[wv], acc, b1, y1b, b, h1, w1i, rbase, m, hl, lane, wv);
        }
        return;
    }

    if (bid >= 42) {                            // ---- zero role ----
        const int pb = bid - 42;
        if (tid >= 124) return;
        int hp, tp;
        if (tid < 32)      { hp = 0;        tp = tid; }
        else if (tid < 64) { hp = 31;       tp = tid - 32; }
        else if (tid < 94) { hp = tid - 63; tp = 0; }
        else               { hp = tid - 93; tp = 31; }
        const size_t off = (size_t)pb * PLANE + hp * 1024 + tp * 32;
        const uint4 z = make_uint4(0, 0, 0, 0);
        *(uint4*)((char*)y1a + off)      = z;
        *(uint4*)((char*)y1a + off + 16) = z;
        *(uint4*)((char*)y1b + off)      = z;
        *(uint4*)((char*)y1b + off + 16) = z;
        *(uint4*)((char*)y2a + off)      = z;
        *(uint4*)((char*)y2a + off + 16) = z;
        *(uint4*)((char*)y2b + off)      = z;
        *(uint4*)((char*)y2b + off + 16) = z;
        return;
    }

    // ---- fragprep role ----
    const int gid = bid * 256 + tid;            // 0..10751
    const int lane = gid & 63;
    const int n = lane & 31, hl = lane >> 5;
    u16 us[8];
#pragma unroll
    for (int j = 0; j < 8; ++j) us[j] = 0;

    if (gid < 6 * 27 * 64) {
        int r = gid >> 6;
        const int k3 = r % 3; r /= 3;
        const int k12 = r % 9; const int set = r / 9;
        const int layer = set >> 1, swap = set & 1;
        const int k1 = k12 / 3, k2 = k12 % 3;
        if (n < 30) {
            const int k4 = (n < 10) ? 0 : ((n < 20) ? 1 : 2);
            const int co = n - 10 * k4;
            const int i1 = swap ? k3 : k1, i2 = swap ? k4 : k2;
            const int i3 = swap ? k1 : k3, i4 = swap ? k2 : k4;
            const int widx = ((i1 * 3 + i2) * 3 + i3) * 3 + i4;
#pragma unroll
            for (int j = 0; j < 8; ++j) {
                const int k = hl * 8 + j;
                float wv = 0.f;
                if (layer == 0) { if (k == 0) wv = w1[co * 81 + widx]; }
                else if (layer == 1) { if (k < 10) wv = w2[(co * 10 + k) * 81 + widx]; }
                else { if (k < 10 && co == 0) wv = w3[k * 81 + widx]; }
                us[j] = f2bf(wv);
            }
        }
    } else {
        const int idx = gid - 6 * 27 * 64;       // 0..383
        int r = idx >> 6;                        // 0..5
        const int k3 = r % 3, swap = r / 3;
        if (n < 30) {
            const int k4 = (n < 10) ? 0 : ((n < 20) ? 1 : 2);
            const int co = n - 10 * k4;
#pragma unroll
            for (int j = 0; j < 8; ++j) {
                const int k12 = hl * 8 + j;
                if (k12 < 9) {
                    const int k1 = k12 / 3, k2 = k12 % 3;
                    const int i1 = swap ? k3 : k1, i2 = swap ? k4 : k2;
                    const int i3 = swap ? k1 : k3, i4 = swap ? k2 : k4;
                    const int widx = ((i1 * 3 + i2) * 3 + i3) * 3 + i4;
                    us[j] = f2bf(w1[co * 81 + widx]);
                }
            }
        }
    }
    u32* o = ft + (size_t)gid * 4;
    o[0] = (u32)us[0] | ((u32)us[1] << 16);
    o[1] = (u32)us[2] | ((u32)us[3] << 16);
    o[2] = (u32)us[4] | ((u32)us[5] << 16);
    o[3] = (u32)us[6] | ((u32)us[7] << 16);
}

// ---------------------------------------------------------------------------
// Standalone prep (middle/fallback paths).
__global__ __launch_bounds__(256) void prep_k(u32* __restrict__ ft,
    const float* __restrict__ w1, const float* __restrict__ w2,
    const float* __restrict__ w3, u16* __restrict__ p1,
    u16* __restrict__ p2, u16* __restrict__ p3, u16* __restrict__ p4)
{
    const int tid = threadIdx.x;
    if (blockIdx.x >= 42) {
        const int pb = blockIdx.x - 42;
        if (tid >= 124) return;
        int hp, tp;
        if (tid < 32)      { hp = 0;        tp = tid; }
        else if (tid < 64) { hp = 31;       tp = tid - 32; }
        else if (tid < 94) { hp = tid - 63; tp = 0; }
        else               { hp = tid - 93; tp = 31; }
        const size_t off = (size_t)pb * PLANE + hp * 1024 + tp * 32;
        const uint4 z = make_uint4(0, 0, 0, 0);
        *(uint4*)((char*)p1 + off)      = z;
        *(uint4*)((char*)p1 + off + 16) = z;
        *(uint4*)((char*)p2 + off)      = z;
        *(uint4*)((char*)p2 + off + 16) = z;
        *(uint4*)((char*)p3 + off)      = z;
        *(uint4*)((char*)p3 + off + 16) = z;
        *(uint4*)((char*)p4 + off)      = z;
        *(uint4*)((char*)p4 + off + 16) = z;
        return;
    }
    const int gid = blockIdx.x * 256 + tid;
    const int lane = gid & 63;
    const int n = lane & 31, hl = lane >> 5;
    u16 us[8];
#pragma unroll
    for (int j = 0; j < 8; ++j) us[j] = 0;

    if (gid < 6 * 27 * 64) {
        int r = gid >> 6;
        const int k3 = r % 3; r /= 3;
        const int k12 = r % 9; const int set = r / 9;
        const int layer = set >> 1, swap = set & 1;
        const int k1 = k12 / 3, k2 = k12 % 3;
        if (n < 30) {
            const int k4 = (n < 10) ? 0 : ((n < 20) ? 1 : 2);
            const int co = n - 10 * k4;
            const int i1 = swap ? k3 : k1, i2 = swap ? k4 : k2;
            const int i3 = swap ? k1 : k3, i4 = swap ? k2 : k4;
            const int widx = ((i1 * 3 + i2) * 3 + i3) * 3 + i4;
#pragma unroll
            for (int j = 0; j < 8; ++j) {
                const int k = hl * 8 + j;
                float wv = 0.f;
                if (layer == 0) { if (k == 0) wv = w1[co * 81 + widx]; }
                else if (layer == 1) { if (k < 10) wv = w2[(co * 10 + k) * 81 + widx]; }
                else { if (k < 10 && co == 0) wv = w3[k * 81 + widx]; }
                us[j] = f2bf(wv);
            }
        }
    } else {
        const int idx = gid - 6 * 27 * 64;
        int r = idx >> 6;
        const int k3 = r % 3, swap = r / 3;
        if (n < 30) {
            const int k4 = (n < 10) ? 0 : ((n < 20) ? 1 : 2);
            const int co = n - 10 * k4;
#pragma unroll
            for (int j = 0; j < 8; ++j) {
                const int k12 = hl * 8 + j;
                if (k12 < 9) {
                    const int k1 = k12 / 3, k2 = k12 % 3;
                    const int i1 = swap ? k3 : k1, i2 = swap ? k4 : k2;
                    const int i3 = swap ? k1 : k3, i4 = swap ? k2 : k4;
                    const int widx = ((i1 * 3 + i2) * 3 + i3) * 3 + i4;
                    us[j] = f2bf(w1[co * 81 + widx]);
                }
            }
        }
    }
    u32* o = ft + (size_t)gid * 4;
    o[0] = (u32)us[0] | ((u32)us[1] << 16);
    o[1] = (u32)us[2] | ((u32)us[3] << 16);
    o[2] = (u32)us[4] | ((u32)us[5] << 16);
    o[3] = (u32)us[6] | ((u32)us[7] << 16);
}

// ---------------------------------------------------------------------------
// Layer 0, single branch (fallback path).
__global__ __launch_bounds__(256, 4) void conv0_k(
    const float* __restrict__ x, const uint4* __restrict__ bt,
    const float* __restrict__ bias, void* __restrict__ outp)
{
    __shared__ float E[4][1056];
    const int wgid = blockIdx.x + S * blockIdx.y + 900 * blockIdx.z;
    const int id2  = (wgid & 7) * 450 + (wgid >> 3);
    const int half = id2 & 1;
    int sp = id2 >> 1;
    const int w1i = sp % S; sp /= S;
    const int h1  = sp % S;
    const int b   = sp / S;
    const int tid = threadIdx.x;
    const int lane = tid & 63, wv = tid >> 6;
    const int m = lane & 31, hl = lane >> 5;
    const int rbase = half * 15 + wv * 4;

    uint4 Bs[3];
#pragma unroll
    for (int ss = 0; ss < 3; ++ss) Bs[ss] = bt[ss * 64 + lane];

    uint4 F[6];
    l0_frags(x, b, h1, w1i, rbase, m, hl, F);

    f32x16 acc[4];
#pragma unroll
    for (int r = 0; r < 4; ++r)
#pragma unroll
        for (int e = 0; e < 16; ++e) acc[r][e] = 0.f;
#pragma unroll
    for (int ss = 0; ss < 3; ++ss)
#pragma unroll
        for (int r = 0; r < 4; ++r)
            acc[r] = __builtin_amdgcn_mfma_f32_32x32x16_bf16(
                __builtin_bit_cast(bf16x8, F[r + ss]),
                __builtin_bit_cast(bf16x8, Bs[ss]), acc[r], 0, 0, 0);

    plane_epilogue(E[wv], acc, bias, outp, b, h1, w1i, rbase, m, hl, lane, wv);
}

// ---------------------------------------------------------------------------
// Layer 0, both branches, table-based (middle path).
__global__ __launch_bounds__(256, 2) void conv0ab_k(
    const float* __restrict__ x, const uint4* __restrict__ bt,
    const float* __restrict__ bias, void* __restrict__ y1a,
    void* __restrict__ y1b)
{
    __shared__ float E[4][1056];
    const int wgid = blockIdx.x + S * blockIdx.y + 900 * blockIdx.z;
    const int id2  = (wgid & 7) * 450 + (wgid >> 3);
    const int half = id2 & 1;
    int sp = id2 >> 1;
    const int w1i = sp % S; sp /= S;
    const int h1  = sp % S;
    const int b   = sp / S;
    const int tid = threadIdx.x;
    const int lane = tid & 63, wv = tid >> 6;
    const int m = lane & 31, hl = lane >> 5;
    const int rbase = half * 15 + wv * 4;

    uint4 F[6];
    l0_frags(x, b, h1, w1i, rbase, m, hl, F);

    f32x16 acc[4];
    {
        uint4 Bs[3];
#pragma unroll
        for (int ss = 0; ss < 3; ++ss) Bs[ss] = bt[ss * 64 + lane];
#pragma unroll
        for (int r = 0; r < 4; ++r)
#pragma unroll
            for (int e = 0; e < 16; ++e) acc[r][e] = 0.f;
#pragma unroll
        for (int ss = 0; ss < 3; ++ss)
#pragma unroll
            for (int r = 0; r < 4; ++r)
                acc[r] = __builtin_amdgcn_mfma_f32_32x32x16_bf16(
                    __builtin_bit_cast(bf16x8, F[r + ss]),
                    __builtin_bit_cast(bf16x8, Bs[ss]), acc[r], 0, 0, 0);
        plane_epilogue(E[wv], acc, bias, y1a, b, h1, w1i, rbase, m, hl, lane, wv);
    }
    {
        uint4 Bs[3];
#pragma unroll
        for (int ss = 0; ss < 3; ++ss) Bs[ss] = bt[192 + ss * 64 + lane];
#pragma unroll
        for (int r = 0; r < 4; ++r)
#pragma unroll
            for (int e = 0; e < 16; ++e) acc[r][e] = 0.f;
#pragma unroll
        for (int ss = 0; ss < 3; ++ss)
#pragma unroll
            for (int r = 0; r < 4; ++r)
                acc[r] = __builtin_amdgcn_mfma_f32_32x32x16_bf16(
                    __builtin_bit_cast(bf16x8, F[r + ss]),
                    __builtin_bit_cast(bf16x8, Bs[ss]), acc[r], 0, 0, 0);
        plane_epilogue(E[wv], acc, bias, y1b, b, h1, w1i, rbase, m, hl, lane, wv);
    }
}

// ---------------------------------------------------------------------------
// Layers 1/2 (R17, byte-identical): fallback path.
template<int LAYER, bool ACCUM>
__global__ __launch_bounds__(256, 2) void conv_k(
    const void* __restrict__ inp, const u32* __restrict__ ftab,
    const float* __restrict__ bias, void* __restrict__ outp)
{
    __shared__ float E[4][1056];
    __shared__ uint4 BT[1728];

    const int tid = threadIdx.x;
    {
        const uint4* g = (const uint4*)ftab;
#pragma unroll
        for (int j = 0; j < 7; ++j) {
            const int idx = j * 256 + tid;
            if (idx < 1728) BT[idx] = g[idx];
        }
    }
    __syncthreads();

    const int wgid = blockIdx.x + S * blockIdx.y + 900 * blockIdx.z;
    const int id2  = (wgid & 7) * 450 + (wgid >> 3);
    const int half = id2 & 1;
    int sp = id2 >> 1;
    const int w1i = sp % S; sp /= S;
    const int h1  = sp % S;
    const int b   = sp / S;

    const int lane = tid & 63, wv = tid >> 6;
    const int m = lane & 31, hl = lane >> 5;
    const int rbase = half * 15 + wv * 4;

    int rofs[6];
#pragma unroll
    for (int f = 0; f < 6; ++f) {
        int rr = rbase + f; if (rr > 31) rr = 31;
        rofs[f] = rr * 1024;
    }

    int kl[9], nk = 0;
#pragma unroll
    for (int k12 = 0; k12 < 9; ++k12) {
        const int g1 = h1 + k12 / 3 - 1, g2 = w1i + k12 % 3 - 1;
        if (g1 >= 0 && g1 < S && g2 >= 0 && g2 < S)
            kl[nk++] = (g1 * S + g2) | (k12 << 10);
    }

    f32x16 acc[4];
#pragma unroll
    for (int r = 0; r < 4; ++r)
#pragma unroll
        for (int e = 0; e < 16; ++e) acc[r][e] = 0.f;

    auto loadA = [&](uint4* Fd, int g) {
        const char* P = (const char*)inp + ((size_t)b * 900 + g) * PLANE
                        + m * 32 + hl * 16;
#pragma unroll
        for (int f = 0; f < 6; ++f)
            Fd[f] = *(const uint4*)(P + rofs[f]);
    };

    uint4 B0[3];
    {
        const int k0 = kl[0] >> 10;
#pragma unroll
        for (int f = 0; f < 3; ++f) B0[f] = BT[(k0 * 3 + f) * 64 + lane];
    }
    uint4 F[6];
    loadA(F, kl[0] & 1023);

    for (int ki = 0; ki + 1 < nk; ++ki) {
        const int gn = kl[ki + 1] & 1023, kn = kl[ki + 1] >> 10;
        uint4 FN[6];
        loadA(FN, gn);
        uint4 BN[3];
#pragma unroll
        for (int f = 0; f < 3; ++f) BN[f] = BT[(kn * 3 + f) * 64 + lane];

#pragma unroll
        for (int ss = 0; ss < 3; ++ss)
#pragma unroll
            for (int r = 0; r < 4; ++r)
                acc[r] = __builtin_amdgcn_mfma_f32_32x32x16_bf16(
                    __builtin_bit_cast(bf16x8, F[r + ss]),
                    __builtin_bit_cast(bf16x8, B0[ss]), acc[r], 0, 0, 0);

#pragma unroll
        for (int f = 0; f < 6; ++f) F[f] = FN[f];
#pragma unroll
        for (int f = 0; f < 3; ++f) B0[f] = BN[f];
    }
#pragma unroll
    for (int ss = 0; ss < 3; ++ss)
#pragma unroll
        for (int r = 0; r < 4; ++r)
            acc[r] = __builtin_amdgcn_mfma_f32_32x32x16_bf16(
                __builtin_bit_cast(bf16x8, F[r + ss]),
                __builtin_bit_cast(bf16x8, B0[ss]), acc[r], 0, 0, 0);

    float* Ew = E[wv];
    for (int r = 0; r < 4; ++r) {
        if (wv == 3 && r == 3) continue;
#pragma unroll
        for (int gq = 0; gq < 4; ++gq)
#pragma unroll
            for (int r4 = 0; r4 < 4; ++r4)
                Ew[m * 33 + 4 * hl + 8 * gq + r4] = acc[r][gq * 4 + r4];

        const int h2 = rbase + r;
        if (LAYER <= 1) {
            char* pl = (char*)outp + ((size_t)b * 900 + h1 * S + w1i) * PLANE
                       + (size_t)(h2 + 1) * 1024;
            const int t = lane >> 1, h8 = lane & 1;
            if (t < 30) {
                u32 wo[4];
#pragma unroll
                for (int p = 0; p < 4; ++p) {
                    const int c0 = 8 * h8 + 2 * p, c1 = c0 + 1;
                    float v0 = 0.f, v1 = 0.f;
                    if (c0 < 10)
                        v0 = fmaxf(Ew[c0 * 33 + t] + Ew[(10 + c0) * 33 + t + 1]
                                 + Ew[(20 + c0) * 33 + t + 2] + bias[c0], 0.f);
                    if (c1 < 10)
                        v1 = fmaxf(Ew[c1 * 33 + t] + Ew[(10 + c1) * 33 + t + 1]
                                 + Ew[(20 + c1) * 33 + t + 2] + bias[c1], 0.f);
                    wo[p] = (u32)f2bf(v0) | ((u32)f2bf(v1) << 16);
                }
                *(uint4*)(pl + (t + 1) * 32 + h8 * 16) =
                    make_uint4(wo[0], wo[1], wo[2], wo[3]);
            }
        } else {
            if (lane < 30) {
                const int t = lane;
                float v = Ew[t] + Ew[330 + t + 1] + Ew[660 + t + 2] + bias[0];
                v = fmaxf(v, 0.f);
                float* o = (float*)outp + (size_t)b * S4
                           + (size_t)(h1 * S + w1i) * 900 + h2 * 30 + t;
                if (ACCUM) *o += v; else *o = v;
            }
        }
    }
}

// ---------------------------------------------------------------------------
// Layer 1, BOTH branches in one z=8 dispatch (byte-identical to R25).
__global__ __launch_bounds__(256, 2) void conv1ab_k(
    const void* __restrict__ y1a, const void* __restrict__ y1b,
    const u32* __restrict__ fta, const u32* __restrict__ ftb,
    const float* __restrict__ bias, void* __restrict__ y2a,
    void* __restrict__ y2b)
{
    __shared__ float E[4][1056];
    __shared__ uint4 BT[1728];

    const int br = blockIdx.z >> 2;
    const int zq = blockIdx.z & 3;
    const void* inp = br ? y1b : y1a;
    const u32* ftab = br ? ftb : fta;
    void* outp = br ? y2b : y2a;

    const int tid = threadIdx.x;
    {
        const uint4* g = (const uint4*)ftab;
#pragma unroll
        for (int j = 0; j < 7; ++j) {
            const int idx = j * 256 + tid;
            if (idx < 1728) BT[idx] = g[idx];
        }
    }
    __syncthreads();

    const int wgid = blockIdx.x + S * blockIdx.y + 900 * zq;
    const int id2  = (wgid & 7) * 450 + (wgid >> 3);
    const int half = id2 & 1;
    int sp = id2 >> 1;
    const int w1i = sp % S; sp /= S;
    const int h1  = sp % S;
    const int b   = sp / S;

    const int lane = tid & 63, wv = tid >> 6;
    const int m = lane & 31, hl = lane >> 5;
    const int rbase = half * 15 + wv * 4;

    int rofs[6];
#pragma unroll
    for (int f = 0; f < 6; ++f) {
        int rr = rbase + f; if (rr > 31) rr = 31;
        rofs[f] = rr * 1024;
    }

    int kl[9], nk = 0;
#pragma unroll
    for (int k12 = 0; k12 < 9; ++k12) {
        const int g1 = h1 + k12 / 3 - 1, g2 = w1i + k12 % 3 - 1;
        if (g1 >= 0 && g1 < S && g2 >= 0 && g2 < S)
            kl[nk++] = (g1 * S + g2) | (k12 << 10);
    }

    f32x16 acc[4];
#pragma unroll
    for (int r = 0; r < 4; ++r)
#pragma unroll
        for (int e = 0; e < 16; ++e) acc[r][e] = 0.f;

    auto loadA = [&](uint4* Fd, int g) {
        const char* P = (const char*)inp + ((size_t)b * 900 + g) * PLANE
                        + m * 32 + hl * 16;
#pragma unroll
        for (int f = 0; f < 6; ++f)
            Fd[f] = *(const uint4*)(P + rofs[f]);
    };

    uint4 B0[3];
    {
        const int k0 = kl[0] >> 10;
#pragma unroll
        for (int f = 0; f < 3; ++f) B0[f] = BT[(k0 * 3 + f) * 64 + lane];
    }
    uint4 F[6];
    loadA(F, kl[0] & 1023);

    for (int ki = 0; ki + 1 < nk; ++ki) {
        const int gn = kl[ki + 1] & 1023, kn = kl[ki + 1] >> 10;
        uint4 FN[6];
        loadA(FN, gn);
        uint4 BN[3];
#pragma unroll
        for (int f = 0; f < 3; ++f) BN[f] = BT[(kn * 3 + f) * 64 + lane];

#pragma unroll
        for (int ss = 0; ss < 3; ++ss)
#pragma unroll
            for (int r = 0; r < 4; ++r)
                acc[r] = __builtin_amdgcn_mfma_f32_32x32x16_bf16(
                    __builtin_bit_cast(bf16x8, F[r + ss]),
                    __builtin_bit_cast(bf16x8, B0[ss]), acc[r], 0, 0, 0);

#pragma unroll
        for (int f = 0; f < 6; ++f) F[f] = FN[f];
#pragma unroll
        for (int f = 0; f < 3; ++f) B0[f] = BN[f];
    }
#pragma unroll
    for (int ss = 0; ss < 3; ++ss)
#pragma unroll
        for (int r = 0; r < 4; ++r)
            acc[r] = __builtin_amdgcn_mfma_f32_32x32x16_bf16(
                __builtin_bit_cast(bf16x8, F[r + ss]),
                __builtin_bit_cast(bf16x8, B0[ss]), acc[r], 0, 0, 0);

    plane_epilogue(E[wv], acc, bias, outp, b, h1, w1i, rbase, m, hl, lane, wv);
}

// ---------------------------------------------------------------------------
// Layer 2, BOTH branches (byte-identical to R25).
__global__ __launch_bounds__(256, 2) void conv2ab_k(
    const void* __restrict__ y2a, const void* __restrict__ y2b,
    const u32* __restrict__ fta, const u32* __restrict__ ftb,
    const float* __restrict__ bias, float* __restrict__ out)
{
    __shared__ uint4 BTS[2][1728];        // branch tables; E overlays BTS[0]

    const int tid = threadIdx.x;
    {
        const uint4* ga = (const uint4*)fta;
        const uint4* gb = (const uint4*)ftb;
#pragma unroll
        for (int j = 0; j < 7; ++j) {
            const int idx = j * 256 + tid;
            if (idx < 1728) { BTS[0][idx] = ga[idx]; BTS[1][idx] = gb[idx]; }
        }
    }
    __syncthreads();

    const int wgid = blockIdx.x + S * blockIdx.y + 900 * blockIdx.z;
    const int id2  = (wgid & 7) * 450 + (wgid >> 3);
    const int half = id2 & 1;
    int sp = id2 >> 1;
    const int w1i = sp % S; sp /= S;
    const int h1  = sp % S;
    const int b   = sp / S;

    const int lane = tid & 63, wv = tid >> 6;
    const int m = lane & 31, hl = lane >> 5;
    const int rbase = half * 15 + wv * 4;

    int rofs[6];
#pragma unroll
    for (int f = 0; f < 6; ++f) {
        int rr = rbase + f; if (rr > 31) rr = 31;
        rofs[f] = rr * 1024;
    }

    int kl[9], nk = 0;
#pragma unroll
    for (int k12 = 0; k12 < 9; ++k12) {
        const int g1 = h1 + k12 / 3 - 1, g2 = w1i + k12 % 3 - 1;
        if (g1 >= 0 && g1 < S && g2 >= 0 && g2 < S)
            kl[nk++] = (g1 * S + g2) | (k12 << 10);
    }

    f32x16 acc[4];

    auto run_taps = [&](const void* inp, const uint4* BTb) {
#pragma unroll
        for (int r = 0; r < 4; ++r)
#pragma unroll
            for (int e = 0; e < 16; ++e) acc[r][e] = 0.f;
        auto loadA = [&](uint4* Fd, int g) {
            const char* P = (const char*)inp + ((size_t)b * 900 + g) * PLANE
                            + m * 32 + hl * 16;
#pragma unroll
            for (int f = 0; f < 6; ++f)
                Fd[f] = *(const uint4*)(P + rofs[f]);
        };
        uint4 B0[3];
        {
            const int k0 = kl[0] >> 10;
#pragma unroll
            for (int f = 0; f < 3; ++f) B0[f] = BTb[(k0 * 3 + f) * 64 + lane];
        }
        uint4 F[6];
        loadA(F, kl[0] & 1023);
        for (int ki = 0; ki + 1 < nk; ++ki) {
            const int gn = kl[ki + 1] & 1023, kn = kl[ki + 1] >> 10;
            uint4 FN[6];
            loadA(FN, gn);
            uint4 BN[3];
#pragma unroll
            for (int f = 0; f < 3; ++f) BN[f] = BTb[(kn * 3 + f) * 64 + lane];
#pragma unroll
            for (int ss = 0; ss < 3; ++ss)
#pragma unroll
                for (int r = 0; r < 4; ++r)
                    acc[r] = __builtin_amdgcn_mfma_f32_32x32x16_bf16(
                        __builtin_bit_cast(bf16x8, F[r + ss]),
                        __builtin_bit_cast(bf16x8, B0[ss]), acc[r], 0, 0, 0);
#pragma unroll
            for (int f = 0; f < 6; ++f) F[f] = FN[f];
#pragma unroll
            for (int f = 0; f < 3; ++f) B0[f] = BN[f];
        }
#pragma unroll
        for (int ss = 0; ss < 3; ++ss)
#pragma unroll
            for (int r = 0; r < 4; ++r)
                acc[r] = __builtin_amdgcn_mfma_f32_32x32x16_bf16(
                    __builtin_bit_cast(bf16x8, F[r + ss]),
                    __builtin_bit_cast(bf16x8, B0[ss]), acc[r], 0, 0, 0);
    };

    // ---- branch 0 taps ----
    run_taps(y2a, BTS[0]);
    __syncthreads();                      // all waves done with BTS[0]
    float* Ew = (float*)&BTS[0][0] + wv * 1056;   // E overlays dead BTS[0]

    float va[4] = {0.f, 0.f, 0.f, 0.f};
    for (int r = 0; r < 4; ++r) {
        if (wv == 3 && r == 3) continue;
#pragma unroll
        for (int gq = 0; gq < 4; ++gq)
#pragma unroll
            for (int r4 = 0; r4 < 4; ++r4)
                Ew[m * 33 + 4 * hl + 8 * gq + r4] = acc[r][gq * 4 + r4];
        if (lane < 30) {
            const int t = lane;
            va[r] = fmaxf(Ew[t] + Ew[330 + t + 1] + Ew[660 + t + 2] + bias[0], 0.f);
        }
    }

    // ---- branch 1 taps (BTS[1] untouched by E overlay) ----
    run_taps(y2b, BTS[1]);
    for (int r = 0; r < 4; ++r) {
        if (wv == 3 && r == 3) continue;
#pragma unroll
        for (int gq = 0; gq < 4; ++gq)
#pragma unroll
            for (int r4 = 0; r4 < 4; ++r4)
                Ew[m * 33 + 4 * hl + 8 * gq + r4] = acc[r][gq * 4 + r4];
        const int h2 = rbase + r;
        if (lane < 30) {
            const int t = lane;
            float v = fmaxf(Ew[t] + Ew[330 + t + 1] + Ew[660 + t + 2] + bias[0], 0.f);
            out[(size_t)b * S4 + (size_t)(h1 * S + w1i) * 900 + h2 * 30 + t]
                = va[r] + v;
        }
    }
}

// ---------------------------------------------------------------------------
extern "C" void kernel_launch(void* const* d_in, const int* in_sizes, int n_in,
                              void* d_out, int out_size, void* d_ws, size_t ws_size,
                              hipStream_t stream)
{
    const float* x   = (const float*)d_in[0];
    const float* w1p = (const float*)d_in[1];
    const float* b1p = (const float*)d_in[2];
    const float* w2p = (const float*)d_in[3];
    const float* b2p = (const float*)d_in[4];
    const float* w3p = (const float*)d_in[5];
    const float* b3p = (const float*)d_in[6];
    float* out = (float*)d_out;

    u32* ft = (u32*)d_ws;
    const uint4* ftL0 = (const uint4*)d_ws + 6 * 27 * 64;
    u16* y1a = (u16*)((char*)d_ws + 172032);
    u16* y1b = (u16*)((char*)y1a + YBYTES);
    u16* y2a = (u16*)((char*)y1b + YBYTES);

    const u32* f2b0 = ft + (size_t)2 * 27 * 64 * 4;
    const u32* f2b1 = ft + (size_t)3 * 27 * 64 * 4;
    const u32* f3b0 = ft + (size_t)4 * 27 * 64 * 4;
    const u32* f3b1 = ft + (size_t)5 * 27 * 64 * 4;

    dim3 grid(S, S, 4), grid8(S, S, 8), blk(256);

    if (ws_size >= 172032 + 4 * YBYTES) {
        // Merged path: 3 dispatches (prep+conv0 fused, conv1ab, conv2ab).
        u16* y2b = (u16*)((char*)y2a + YBYTES);
        prep0_k<<<5442, blk, 0, stream>>>(ft, w1p, w2p, w3p,
                                          y1a, y1b, y2a, y2b, x, b1p);
        conv1ab_k<<<grid8, blk, 0, stream>>>(y1a, y1b, f2b0, f2b1, b2p,
                                             (void*)y2a, (void*)y2b);
        conv2ab_k<<<grid, blk, 0, stream>>>(y2a, y2b, f3b0, f3b1, b3p, out);
    } else if (ws_size >= 172032 + 3 * YBYTES) {
        // R23 merged path (5 dispatches), alias y2b = y1a (separate
        // dispatches order L1a before L1b).
        u16* y2b = y1a;
        prep_k<<<1842, blk, 0, stream>>>(ft, w1p, w2p, w3p, y1a, y1b, y2a, y2a);
        conv0ab_k<<<grid, blk, 0, stream>>>(x, ftL0, b1p, (void*)y1a, (void*)y1b);
        conv_k<1, false><<<grid, blk, 0, stream>>>(y1a, f2b0, b2p, (void*)y2a);
        conv_k<1, false><<<grid, blk, 0, stream>>>(y1b, f2b1, b2p, (void*)y2b);
        conv2ab_k<<<grid, blk, 0, stream>>>(y2a, y2b, f3b0, f3b1, b3p, out);
    } else {
        // Fallback: exact R22 path (2 buffers: y1a, y1b-as-y2).
        u16* y1 = y1a;
        u16* y2 = y1b;
        prep_k<<<1842, blk, 0, stream>>>(ft, w1p, w2p, w3p, y1, y2, y2, y2);
        for (int br = 0; br < 2; ++br) {
            const u32* f2 = (br == 0) ? f2b0 : f2b1;
            const u32* f3 = (br == 0) ? f3b0 : f3b1;
            conv0_k<<<grid, blk, 0, stream>>>(x, ftL0 + br * 192, b1p, (void*)y1);
            conv_k<1, false><<<grid, blk, 0, stream>>>(y1, f2, b2p, (void*)y2);
            if (br == 0)
                conv_k<2, false><<<grid, blk, 0, stream>>>(y2, f3, b3p, (void*)out);
            else
                conv_k<2, true><<<grid, blk, 0, stream>>>(y2, f3, b3p, (void*)out);
        }
    }
}

// Round 20
// 371.166 us; speedup vs baseline: 1.0049x; 1.0049x over previous
//
#include <hip/hip_runtime.h>

// 4D conv net, MI355X. S=30, B=2, ch 1->10->10->1, kernel 3^4, pad 1, ReLU.
// out = net(x,w) + net(x,w_swap), w_swap has (k1,k2)<->(k3,k4).
// R7-R17: 32x32x16 bf16 MFMA, XCD-chunk swizzle, B-table in LDS, rotate-A
// depth-1 prefetch, barrier-free per-wave epilogue. conv_k = 69.5 us.
// R22 (384): +fused prep. R23 (375): conv0ab/conv2ab branch merges
// (single out store kills RMW). R24/R25 (365.2, CHAMPION): conv1ab z=8
// merge + 4-buffer single-pass prep.
// R26 (reverted): prep+conv0 mega-fusion regressed (373): conv0-role tail
// polluted conv1ab's L2 window; boundary saving < interference cost.
// R27: final — byte-identical resubmission of the R25 champion. Ledger:
// 9 in-kernel levers + 2 further graph merges all regress vs this config.

static constexpr int S  = 30;
static constexpr long S4 = 810000;
static constexpr size_t PLANE = 32768;                  // 32*32*16*2 B
static constexpr size_t YBYTES = (size_t)1800 * PLANE;  // [b(2)][g1][g2]

typedef __bf16 bf16x8 __attribute__((ext_vector_type(8)));
typedef float  f32x16 __attribute__((ext_vector_type(16)));
typedef unsigned int  u32;
typedef unsigned short u16;

static __device__ __forceinline__ u16 f2bf(float f) {
    u32 u = __builtin_bit_cast(u32, f);
    return (u16)((u + 0x7fffu + ((u >> 16) & 1u)) >> 16);
}

// ---------------------------------------------------------------------------
// Fused prep: blocks 0..41 build the B-fragment tables (42*256 = 10752 ids
// exactly); blocks 42..1841 zero halo positions of up to 4 y-buffers.
// Main table: [set(6)][k12(9)][k3(3)][lane(64)] uint4 (sets 0/1 unused).
// L0-packed (appended): [branch(2)][k3(3)][lane(64)] uint4.
__global__ __launch_bounds__(256) void prep_k(u32* __restrict__ ft,
    const float* __restrict__ w1, const float* __restrict__ w2,
    const float* __restrict__ w3, u16* __restrict__ p1,
    u16* __restrict__ p2, u16* __restrict__ p3, u16* __restrict__ p4)
{
    const int tid = threadIdx.x;
    if (blockIdx.x >= 42) {                    // ---- zero role ----
        const int pb = blockIdx.x - 42;
        if (tid >= 124) return;
        int hp, tp;
        if (tid < 32)      { hp = 0;        tp = tid; }
        else if (tid < 64) { hp = 31;       tp = tid - 32; }
        else if (tid < 94) { hp = tid - 63; tp = 0; }
        else               { hp = tid - 93; tp = 31; }
        const size_t off = (size_t)pb * PLANE + hp * 1024 + tp * 32;
        const uint4 z = make_uint4(0, 0, 0, 0);
        *(uint4*)((char*)p1 + off)      = z;
        *(uint4*)((char*)p1 + off + 16) = z;
        *(uint4*)((char*)p2 + off)      = z;
        *(uint4*)((char*)p2 + off + 16) = z;
        *(uint4*)((char*)p3 + off)      = z;
        *(uint4*)((char*)p3 + off + 16) = z;
        *(uint4*)((char*)p4 + off)      = z;
        *(uint4*)((char*)p4 + off + 16) = z;
        return;
    }
    // ---- fragprep role ----
    const int gid = blockIdx.x * 256 + tid;    // 0..10751
    const int lane = gid & 63;
    const int n = lane & 31, hl = lane >> 5;
    u16 us[8];
#pragma unroll
    for (int j = 0; j < 8; ++j) us[j] = 0;

    if (gid < 6 * 27 * 64) {
        int r = gid >> 6;
        const int k3 = r % 3; r /= 3;
        const int k12 = r % 9; const int set = r / 9;
        const int layer = set >> 1, swap = set & 1;
        const int k1 = k12 / 3, k2 = k12 % 3;
        if (n < 30) {
            const int k4 = (n < 10) ? 0 : ((n < 20) ? 1 : 2);
            const int co = n - 10 * k4;
            const int i1 = swap ? k3 : k1, i2 = swap ? k4 : k2;
            const int i3 = swap ? k1 : k3, i4 = swap ? k2 : k4;
            const int widx = ((i1 * 3 + i2) * 3 + i3) * 3 + i4;
#pragma unroll
            for (int j = 0; j < 8; ++j) {
                const int k = hl * 8 + j;
                float wv = 0.f;
                if (layer == 0) { if (k == 0) wv = w1[co * 81 + widx]; }
                else if (layer == 1) { if (k < 10) wv = w2[(co * 10 + k) * 81 + widx]; }
                else { if (k < 10 && co == 0) wv = w3[k * 81 + widx]; }
                us[j] = f2bf(wv);
            }
        }
    } else {
        const int idx = gid - 6 * 27 * 64;       // 0..383
        int r = idx >> 6;                        // 0..5
        const int k3 = r % 3, swap = r / 3;
        if (n < 30) {
            const int k4 = (n < 10) ? 0 : ((n < 20) ? 1 : 2);
            const int co = n - 10 * k4;
#pragma unroll
            for (int j = 0; j < 8; ++j) {
                const int k12 = hl * 8 + j;
                if (k12 < 9) {
                    const int k1 = k12 / 3, k2 = k12 % 3;
                    const int i1 = swap ? k3 : k1, i2 = swap ? k4 : k2;
                    const int i3 = swap ? k1 : k3, i4 = swap ? k2 : k4;
                    const int widx = ((i1 * 3 + i2) * 3 + i3) * 3 + i4;
                    us[j] = f2bf(w1[co * 81 + widx]);
                }
            }
        }
    }
    u32* o = ft + (size_t)gid * 4;
    o[0] = (u32)us[0] | ((u32)us[1] << 16);
    o[1] = (u32)us[2] | ((u32)us[3] << 16);
    o[2] = (u32)us[4] | ((u32)us[5] << 16);
    o[3] = (u32)us[6] | ((u32)us[7] << 16);
}

// ---------------------------------------------------------------------------
// Common L0 A-fragment build + epilogue as device helpers.
static __device__ __forceinline__ void l0_frags(
    const float* __restrict__ x, int b, int h1, int w1i, int rbase,
    int m, int hl, uint4* F)
{
    int gof[9]; int gokm = 0;
#pragma unroll
    for (int k12 = 0; k12 < 9; ++k12) {
        const int g1 = h1 + k12 / 3 - 1, g2 = w1i + k12 % 3 - 1;
        gof[k12] = 0;
        if (g1 >= 0 && g1 < S && g2 >= 0 && g2 < S) {
            gof[k12] = (g1 * S + g2) * 900; gokm |= 1 << k12;
        }
    }
    const float* xb = x + (size_t)b * S4;
#pragma unroll
    for (int f = 0; f < 6; ++f) {
        const int hp = rbase + f;
        const bool rk = (hp >= 1 && hp <= 30 && m >= 1 && m <= 30);
        const int ro = (hp - 1) * 30 + (m - 1);
        u16 av[8];
#pragma unroll
        for (int j = 0; j < 8; ++j) av[j] = 0;
        if (hl == 0) {
#pragma unroll
            for (int j = 0; j < 8; ++j) {
                float v = 0.f;
                if (rk && ((gokm >> j) & 1)) v = xb[gof[j] + ro];
                av[j] = f2bf(v);
            }
        } else {
            float v = 0.f;
            if (rk && ((gokm >> 8) & 1)) v = xb[gof[8] + ro];
            av[0] = f2bf(v);
        }
        F[f] = make_uint4((u32)av[0] | ((u32)av[1] << 16),
                          (u32)av[2] | ((u32)av[3] << 16),
                          (u32)av[4] | ((u32)av[5] << 16),
                          (u32)av[6] | ((u32)av[7] << 16));
    }
}

static __device__ __forceinline__ void plane_epilogue(
    float* Ew, const f32x16* acc, const float* __restrict__ bias,
    void* __restrict__ outp, int b, int h1, int w1i, int rbase,
    int m, int hl, int lane, int wv)
{
    for (int r = 0; r < 4; ++r) {
        if (wv == 3 && r == 3) continue;
#pragma unroll
        for (int gq = 0; gq < 4; ++gq)
#pragma unroll
            for (int r4 = 0; r4 < 4; ++r4)
                Ew[m * 33 + 4 * hl + 8 * gq + r4] = acc[r][gq * 4 + r4];

        const int h2 = rbase + r;
        char* pl = (char*)outp + ((size_t)b * 900 + h1 * S + w1i) * PLANE
                   + (size_t)(h2 + 1) * 1024;
        const int t = lane >> 1, h8 = lane & 1;
        if (t < 30) {
            u32 wo[4];
#pragma unroll
            for (int p = 0; p < 4; ++p) {
                const int c0 = 8 * h8 + 2 * p, c1 = c0 + 1;
                float v0 = 0.f, v1 = 0.f;
                if (c0 < 10)
                    v0 = fmaxf(Ew[c0 * 33 + t] + Ew[(10 + c0) * 33 + t + 1]
                             + Ew[(20 + c0) * 33 + t + 2] + bias[c0], 0.f);
                if (c1 < 10)
                    v1 = fmaxf(Ew[c1 * 33 + t] + Ew[(10 + c1) * 33 + t + 1]
                             + Ew[(20 + c1) * 33 + t + 2] + bias[c1], 0.f);
                wo[p] = (u32)f2bf(v0) | ((u32)f2bf(v1) << 16);
            }
            *(uint4*)(pl + (t + 1) * 32 + h8 * 16) =
                make_uint4(wo[0], wo[1], wo[2], wo[3]);
        }
    }
}

// ---------------------------------------------------------------------------
// Layer 0, single branch (R13, fallback path).
__global__ __launch_bounds__(256, 4) void conv0_k(
    const float* __restrict__ x, const uint4* __restrict__ bt,
    const float* __restrict__ bias, void* __restrict__ outp)
{
    __shared__ float E[4][1056];
    const int wgid = blockIdx.x + S * blockIdx.y + 900 * blockIdx.z;
    const int id2  = (wgid & 7) * 450 + (wgid >> 3);
    const int half = id2 & 1;
    int sp = id2 >> 1;
    const int w1i = sp % S; sp /= S;
    const int h1  = sp % S;
    const int b   = sp / S;
    const int tid = threadIdx.x;
    const int lane = tid & 63, wv = tid >> 6;
    const int m = lane & 31, hl = lane >> 5;
    const int rbase = half * 15 + wv * 4;

    uint4 Bs[3];
#pragma unroll
    for (int ss = 0; ss < 3; ++ss) Bs[ss] = bt[ss * 64 + lane];

    uint4 F[6];
    l0_frags(x, b, h1, w1i, rbase, m, hl, F);

    f32x16 acc[4];
#pragma unroll
    for (int r = 0; r < 4; ++r)
#pragma unroll
        for (int e = 0; e < 16; ++e) acc[r][e] = 0.f;
#pragma unroll
    for (int ss = 0; ss < 3; ++ss)
#pragma unroll
        for (int r = 0; r < 4; ++r)
            acc[r] = __builtin_amdgcn_mfma_f32_32x32x16_bf16(
                __builtin_bit_cast(bf16x8, F[r + ss]),
                __builtin_bit_cast(bf16x8, Bs[ss]), acc[r], 0, 0, 0);

    plane_epilogue(E[wv], acc, bias, outp, b, h1, w1i, rbase, m, hl, lane, wv);
}

// ---------------------------------------------------------------------------
// Layer 0, BOTH branches (merged path): x-fragments loaded once, two MFMA
// sets, two epilogues (y1a, y1b).
__global__ __launch_bounds__(256, 2) void conv0ab_k(
    const float* __restrict__ x, const uint4* __restrict__ bt,
    const float* __restrict__ bias, void* __restrict__ y1a,
    void* __restrict__ y1b)
{
    __shared__ float E[4][1056];
    const int wgid = blockIdx.x + S * blockIdx.y + 900 * blockIdx.z;
    const int id2  = (wgid & 7) * 450 + (wgid >> 3);
    const int half = id2 & 1;
    int sp = id2 >> 1;
    const int w1i = sp % S; sp /= S;
    const int h1  = sp % S;
    const int b   = sp / S;
    const int tid = threadIdx.x;
    const int lane = tid & 63, wv = tid >> 6;
    const int m = lane & 31, hl = lane >> 5;
    const int rbase = half * 15 + wv * 4;

    uint4 F[6];
    l0_frags(x, b, h1, w1i, rbase, m, hl, F);

    f32x16 acc[4];
    // ---- branch 0 ----
    {
        uint4 Bs[3];
#pragma unroll
        for (int ss = 0; ss < 3; ++ss) Bs[ss] = bt[ss * 64 + lane];
#pragma unroll
        for (int r = 0; r < 4; ++r)
#pragma unroll
            for (int e = 0; e < 16; ++e) acc[r][e] = 0.f;
#pragma unroll
        for (int ss = 0; ss < 3; ++ss)
#pragma unroll
            for (int r = 0; r < 4; ++r)
                acc[r] = __builtin_amdgcn_mfma_f32_32x32x16_bf16(
                    __builtin_bit_cast(bf16x8, F[r + ss]),
                    __builtin_bit_cast(bf16x8, Bs[ss]), acc[r], 0, 0, 0);
        plane_epilogue(E[wv], acc, bias, y1a, b, h1, w1i, rbase, m, hl, lane, wv);
    }
    // ---- branch 1 ----
    {
        uint4 Bs[3];
#pragma unroll
        for (int ss = 0; ss < 3; ++ss) Bs[ss] = bt[192 + ss * 64 + lane];
#pragma unroll
        for (int r = 0; r < 4; ++r)
#pragma unroll
            for (int e = 0; e < 16; ++e) acc[r][e] = 0.f;
#pragma unroll
        for (int ss = 0; ss < 3; ++ss)
#pragma unroll
            for (int r = 0; r < 4; ++r)
                acc[r] = __builtin_amdgcn_mfma_f32_32x32x16_bf16(
                    __builtin_bit_cast(bf16x8, F[r + ss]),
                    __builtin_bit_cast(bf16x8, Bs[ss]), acc[r], 0, 0, 0);
        plane_epilogue(E[wv], acc, bias, y1b, b, h1, w1i, rbase, m, hl, lane, wv);
    }
}

// ---------------------------------------------------------------------------
// Layers 1/2 (R17, byte-identical): fallback path.
template<int LAYER, bool ACCUM>
__global__ __launch_bounds__(256, 2) void conv_k(
    const void* __restrict__ inp, const u32* __restrict__ ftab,
    const float* __restrict__ bias, void* __restrict__ outp)
{
    __shared__ float E[4][1056];
    __shared__ uint4 BT[1728];

    const int tid = threadIdx.x;
    {
        const uint4* g = (const uint4*)ftab;
#pragma unroll
        for (int j = 0; j < 7; ++j) {
            const int idx = j * 256 + tid;
            if (idx < 1728) BT[idx] = g[idx];
        }
    }
    __syncthreads();

    const int wgid = blockIdx.x + S * blockIdx.y + 900 * blockIdx.z;
    const int id2  = (wgid & 7) * 450 + (wgid >> 3);
    const int half = id2 & 1;
    int sp = id2 >> 1;
    const int w1i = sp % S; sp /= S;
    const int h1  = sp % S;
    const int b   = sp / S;

    const int lane = tid & 63, wv = tid >> 6;
    const int m = lane & 31, hl = lane >> 5;
    const int rbase = half * 15 + wv * 4;

    int rofs[6];
#pragma unroll
    for (int f = 0; f < 6; ++f) {
        int rr = rbase + f; if (rr > 31) rr = 31;
        rofs[f] = rr * 1024;
    }

    int kl[9], nk = 0;
#pragma unroll
    for (int k12 = 0; k12 < 9; ++k12) {
        const int g1 = h1 + k12 / 3 - 1, g2 = w1i + k12 % 3 - 1;
        if (g1 >= 0 && g1 < S && g2 >= 0 && g2 < S)
            kl[nk++] = (g1 * S + g2) | (k12 << 10);
    }

    f32x16 acc[4];
#pragma unroll
    for (int r = 0; r < 4; ++r)
#pragma unroll
        for (int e = 0; e < 16; ++e) acc[r][e] = 0.f;

    auto loadA = [&](uint4* Fd, int g) {
        const char* P = (const char*)inp + ((size_t)b * 900 + g) * PLANE
                        + m * 32 + hl * 16;
#pragma unroll
        for (int f = 0; f < 6; ++f)
            Fd[f] = *(const uint4*)(P + rofs[f]);
    };

    uint4 B0[3];
    {
        const int k0 = kl[0] >> 10;
#pragma unroll
        for (int f = 0; f < 3; ++f) B0[f] = BT[(k0 * 3 + f) * 64 + lane];
    }
    uint4 F[6];
    loadA(F, kl[0] & 1023);

    for (int ki = 0; ki + 1 < nk; ++ki) {
        const int gn = kl[ki + 1] & 1023, kn = kl[ki + 1] >> 10;
        uint4 FN[6];
        loadA(FN, gn);
        uint4 BN[3];
#pragma unroll
        for (int f = 0; f < 3; ++f) BN[f] = BT[(kn * 3 + f) * 64 + lane];

#pragma unroll
        for (int ss = 0; ss < 3; ++ss)
#pragma unroll
            for (int r = 0; r < 4; ++r)
                acc[r] = __builtin_amdgcn_mfma_f32_32x32x16_bf16(
                    __builtin_bit_cast(bf16x8, F[r + ss]),
                    __builtin_bit_cast(bf16x8, B0[ss]), acc[r], 0, 0, 0);

#pragma unroll
        for (int f = 0; f < 6; ++f) F[f] = FN[f];
#pragma unroll
        for (int f = 0; f < 3; ++f) B0[f] = BN[f];
    }
#pragma unroll
    for (int ss = 0; ss < 3; ++ss)
#pragma unroll
        for (int r = 0; r < 4; ++r)
            acc[r] = __builtin_amdgcn_mfma_f32_32x32x16_bf16(
                __builtin_bit_cast(bf16x8, F[r + ss]),
                __builtin_bit_cast(bf16x8, B0[ss]), acc[r], 0, 0, 0);

    float* Ew = E[wv];
    for (int r = 0; r < 4; ++r) {
        if (wv == 3 && r == 3) continue;
#pragma unroll
        for (int gq = 0; gq < 4; ++gq)
#pragma unroll
            for (int r4 = 0; r4 < 4; ++r4)
                Ew[m * 33 + 4 * hl + 8 * gq + r4] = acc[r][gq * 4 + r4];

        const int h2 = rbase + r;
        if (LAYER <= 1) {
            char* pl = (char*)outp + ((size_t)b * 900 + h1 * S + w1i) * PLANE
                       + (size_t)(h2 + 1) * 1024;
            const int t = lane >> 1, h8 = lane & 1;
            if (t < 30) {
                u32 wo[4];
#pragma unroll
                for (int p = 0; p < 4; ++p) {
                    const int c0 = 8 * h8 + 2 * p, c1 = c0 + 1;
                    float v0 = 0.f, v1 = 0.f;
                    if (c0 < 10)
                        v0 = fmaxf(Ew[c0 * 33 + t] + Ew[(10 + c0) * 33 + t + 1]
                                 + Ew[(20 + c0) * 33 + t + 2] + bias[c0], 0.f);
                    if (c1 < 10)
                        v1 = fmaxf(Ew[c1 * 33 + t] + Ew[(10 + c1) * 33 + t + 1]
                                 + Ew[(20 + c1) * 33 + t + 2] + bias[c1], 0.f);
                    wo[p] = (u32)f2bf(v0) | ((u32)f2bf(v1) << 16);
                }
                *(uint4*)(pl + (t + 1) * 32 + h8 * 16) =
                    make_uint4(wo[0], wo[1], wo[2], wo[3]);
            }
        } else {
            if (lane < 30) {
                const int t = lane;
                float v = Ew[t] + Ew[330 + t + 1] + Ew[660 + t + 2] + bias[0];
                v = fmaxf(v, 0.f);
                float* o = (float*)outp + (size_t)b * S4
                           + (size_t)(h1 * S + w1i) * 900 + h2 * 30 + t;
                if (ACCUM) *o += v; else *o = v;
            }
        }
    }
}

// ---------------------------------------------------------------------------
// Layer 1, BOTH branches in one z=8 dispatch: branch = z>>2 (wave-uniform),
// zq = z&3. Body identical to conv_k<1>; each block touches only its own
// branch's buffers; z-order separates branches temporally in L2.
__global__ __launch_bounds__(256, 2) void conv1ab_k(
    const void* __restrict__ y1a, const void* __restrict__ y1b,
    const u32* __restrict__ fta, const u32* __restrict__ ftb,
    const float* __restrict__ bias, void* __restrict__ y2a,
    void* __restrict__ y2b)
{
    __shared__ float E[4][1056];
    __shared__ uint4 BT[1728];

    const int br = blockIdx.z >> 2;
    const int zq = blockIdx.z & 3;
    const void* inp = br ? y1b : y1a;
    const u32* ftab = br ? ftb : fta;
    void* outp = br ? y2b : y2a;

    const int tid = threadIdx.x;
    {
        const uint4* g = (const uint4*)ftab;
#pragma unroll
        for (int j = 0; j < 7; ++j) {
            const int idx = j * 256 + tid;
            if (idx < 1728) BT[idx] = g[idx];
        }
    }
    __syncthreads();

    const int wgid = blockIdx.x + S * blockIdx.y + 900 * zq;
    const int id2  = (wgid & 7) * 450 + (wgid >> 3);
    const int half = id2 & 1;
    int sp = id2 >> 1;
    const int w1i = sp % S; sp /= S;
    const int h1  = sp % S;
    const int b   = sp / S;

    const int lane = tid & 63, wv = tid >> 6;
    const int m = lane & 31, hl = lane >> 5;
    const int rbase = half * 15 + wv * 4;

    int rofs[6];
#pragma unroll
    for (int f = 0; f < 6; ++f) {
        int rr = rbase + f; if (rr > 31) rr = 31;
        rofs[f] = rr * 1024;
    }

    int kl[9], nk = 0;
#pragma unroll
    for (int k12 = 0; k12 < 9; ++k12) {
        const int g1 = h1 + k12 / 3 - 1, g2 = w1i + k12 % 3 - 1;
        if (g1 >= 0 && g1 < S && g2 >= 0 && g2 < S)
            kl[nk++] = (g1 * S + g2) | (k12 << 10);
    }

    f32x16 acc[4];
#pragma unroll
    for (int r = 0; r < 4; ++r)
#pragma unroll
        for (int e = 0; e < 16; ++e) acc[r][e] = 0.f;

    auto loadA = [&](uint4* Fd, int g) {
        const char* P = (const char*)inp + ((size_t)b * 900 + g) * PLANE
                        + m * 32 + hl * 16;
#pragma unroll
        for (int f = 0; f < 6; ++f)
            Fd[f] = *(const uint4*)(P + rofs[f]);
    };

    uint4 B0[3];
    {
        const int k0 = kl[0] >> 10;
#pragma unroll
        for (int f = 0; f < 3; ++f) B0[f] = BT[(k0 * 3 + f) * 64 + lane];
    }
    uint4 F[6];
    loadA(F, kl[0] & 1023);

    for (int ki = 0; ki + 1 < nk; ++ki) {
        const int gn = kl[ki + 1] & 1023, kn = kl[ki + 1] >> 10;
        uint4 FN[6];
        loadA(FN, gn);
        uint4 BN[3];
#pragma unroll
        for (int f = 0; f < 3; ++f) BN[f] = BT[(kn * 3 + f) * 64 + lane];

#pragma unroll
        for (int ss = 0; ss < 3; ++ss)
#pragma unroll
            for (int r = 0; r < 4; ++r)
                acc[r] = __builtin_amdgcn_mfma_f32_32x32x16_bf16(
                    __builtin_bit_cast(bf16x8, F[r + ss]),
                    __builtin_bit_cast(bf16x8, B0[ss]), acc[r], 0, 0, 0);

#pragma unroll
        for (int f = 0; f < 6; ++f) F[f] = FN[f];
#pragma unroll
        for (int f = 0; f < 3; ++f) B0[f] = BN[f];
    }
#pragma unroll
    for (int ss = 0; ss < 3; ++ss)
#pragma unroll
        for (int r = 0; r < 4; ++r)
            acc[r] = __builtin_amdgcn_mfma_f32_32x32x16_bf16(
                __builtin_bit_cast(bf16x8, F[r + ss]),
                __builtin_bit_cast(bf16x8, B0[ss]), acc[r], 0, 0, 0);

    plane_epilogue(E[wv], acc, bias, outp, b, h1, w1i, rbase, m, hl, lane, wv);
}

// ---------------------------------------------------------------------------
// Layer 2, BOTH branches (merged path): taps over y2a then y2b; epilogue-a
// stashed in registers; single out store (no RMW). LDS: both B-tables;
// E overlays dead BTS[0] behind a barrier after taps-a.
__global__ __launch_bounds__(256, 2) void conv2ab_k(
    const void* __restrict__ y2a, const void* __restrict__ y2b,
    const u32* __restrict__ fta, const u32* __restrict__ ftb,
    const float* __restrict__ bias, float* __restrict__ out)
{
    __shared__ uint4 BTS[2][1728];        // branch tables; E overlays BTS[0]

    const int tid = threadIdx.x;
    {
        const uint4* ga = (const uint4*)fta;
        const uint4* gb = (const uint4*)ftb;
#pragma unroll
        for (int j = 0; j < 7; ++j) {
            const int idx = j * 256 + tid;
            if (idx < 1728) { BTS[0][idx] = ga[idx]; BTS[1][idx] = gb[idx]; }
        }
    }
    __syncthreads();

    const int wgid = blockIdx.x + S * blockIdx.y + 900 * blockIdx.z;
    const int id2  = (wgid & 7) * 450 + (wgid >> 3);
    const int half = id2 & 1;
    int sp = id2 >> 1;
    const int w1i = sp % S; sp /= S;
    const int h1  = sp % S;
    const int b   = sp / S;

    const int lane = tid & 63, wv = tid >> 6;
    const int m = lane & 31, hl = lane >> 5;
    const int rbase = half * 15 + wv * 4;

    int rofs[6];
#pragma unroll
    for (int f = 0; f < 6; ++f) {
        int rr = rbase + f; if (rr > 31) rr = 31;
        rofs[f] = rr * 1024;
    }

    int kl[9], nk = 0;
#pragma unroll
    for (int k12 = 0; k12 < 9; ++k12) {
        const int g1 = h1 + k12 / 3 - 1, g2 = w1i + k12 % 3 - 1;
        if (g1 >= 0 && g1 < S && g2 >= 0 && g2 < S)
            kl[nk++] = (g1 * S + g2) | (k12 << 10);
    }

    f32x16 acc[4];

    auto run_taps = [&](const void* inp, const uint4* BTb) {
#pragma unroll
        for (int r = 0; r < 4; ++r)
#pragma unroll
            for (int e = 0; e < 16; ++e) acc[r][e] = 0.f;
        auto loadA = [&](uint4* Fd, int g) {
            const char* P = (const char*)inp + ((size_t)b * 900 + g) * PLANE
                            + m * 32 + hl * 16;
#pragma unroll
            for (int f = 0; f < 6; ++f)
                Fd[f] = *(const uint4*)(P + rofs[f]);
        };
        uint4 B0[3];
        {
            const int k0 = kl[0] >> 10;
#pragma unroll
            for (int f = 0; f < 3; ++f) B0[f] = BTb[(k0 * 3 + f) * 64 + lane];
        }
        uint4 F[6];
        loadA(F, kl[0] & 1023);
        for (int ki = 0; ki + 1 < nk; ++ki) {
            const int gn = kl[ki + 1] & 1023, kn = kl[ki + 1] >> 10;
            uint4 FN[6];
            loadA(FN, gn);
            uint4 BN[3];
#pragma unroll
            for (int f = 0; f < 3; ++f) BN[f] = BTb[(kn * 3 + f) * 64 + lane];
#pragma unroll
            for (int ss = 0; ss < 3; ++ss)
#pragma unroll
                for (int r = 0; r < 4; ++r)
                    acc[r] = __builtin_amdgcn_mfma_f32_32x32x16_bf16(
                        __builtin_bit_cast(bf16x8, F[r + ss]),
                        __builtin_bit_cast(bf16x8, B0[ss]), acc[r], 0, 0, 0);
#pragma unroll
            for (int f = 0; f < 6; ++f) F[f] = FN[f];
#pragma unroll
            for (int f = 0; f < 3; ++f) B0[f] = BN[f];
        }
#pragma unroll
        for (int ss = 0; ss < 3; ++ss)
#pragma unroll
            for (int r = 0; r < 4; ++r)
                acc[r] = __builtin_amdgcn_mfma_f32_32x32x16_bf16(
                    __builtin_bit_cast(bf16x8, F[r + ss]),
                    __builtin_bit_cast(bf16x8, B0[ss]), acc[r], 0, 0, 0);
    };

    // ---- branch 0 taps ----
    run_taps(y2a, BTS[0]);
    __syncthreads();                      // all waves done with BTS[0]
    float* Ew = (float*)&BTS[0][0] + wv * 1056;   // E overlays dead BTS[0]

    float va[4] = {0.f, 0.f, 0.f, 0.f};
    for (int r = 0; r < 4; ++r) {
        if (wv == 3 && r == 3) continue;
#pragma unroll
        for (int gq = 0; gq < 4; ++gq)
#pragma unroll
            for (int r4 = 0; r4 < 4; ++r4)
                Ew[m * 33 + 4 * hl + 8 * gq + r4] = acc[r][gq * 4 + r4];
        if (lane < 30) {
            const int t = lane;
            va[r] = fmaxf(Ew[t] + Ew[330 + t + 1] + Ew[660 + t + 2] + bias[0], 0.f);
        }
    }

    // ---- branch 1 taps (BTS[1] untouched by E overlay) ----
    run_taps(y2b, BTS[1]);
    for (int r = 0; r < 4; ++r) {
        if (wv == 3 && r == 3) continue;
#pragma unroll
        for (int gq = 0; gq < 4; ++gq)
#pragma unroll
            for (int r4 = 0; r4 < 4; ++r4)
                Ew[m * 33 + 4 * hl + 8 * gq + r4] = acc[r][gq * 4 + r4];
        const int h2 = rbase + r;
        if (lane < 30) {
            const int t = lane;
            float v = fmaxf(Ew[t] + Ew[330 + t + 1] + Ew[660 + t + 2] + bias[0], 0.f);
            out[(size_t)b * S4 + (size_t)(h1 * S + w1i) * 900 + h2 * 30 + t]
                = va[r] + v;
        }
    }
}

// ---------------------------------------------------------------------------
extern "C" void kernel_launch(void* const* d_in, const int* in_sizes, int n_in,
                              void* d_out, int out_size, void* d_ws, size_t ws_size,
                              hipStream_t stream)
{
    const float* x   = (const float*)d_in[0];
    const float* w1p = (const float*)d_in[1];
    const float* b1p = (const float*)d_in[2];
    const float* w2p = (const float*)d_in[3];
    const float* b2p = (const float*)d_in[4];
    const float* w3p = (const float*)d_in[5];
    const float* b3p = (const float*)d_in[6];
    float* out = (float*)d_out;

    u32* ft = (u32*)d_ws;
    const uint4* ftL0 = (const uint4*)d_ws + 6 * 27 * 64;
    u16* y1a = (u16*)((char*)d_ws + 172032);
    u16* y1b = (u16*)((char*)y1a + YBYTES);
    u16* y2a = (u16*)((char*)y1b + YBYTES);

    const u32* f2b0 = ft + (size_t)2 * 27 * 64 * 4;
    const u32* f2b1 = ft + (size_t)3 * 27 * 64 * 4;
    const u32* f3b0 = ft + (size_t)4 * 27 * 64 * 4;
    const u32* f3b1 = ft + (size_t)5 * 27 * 64 * 4;

    dim3 grid(S, S, 4), grid8(S, S, 8), blk(256);

    if (ws_size >= 172032 + 4 * YBYTES) {
        // Merged path: 5 dispatches (1 prep + 4 conv).
        u16* y2b = (u16*)((char*)y2a + YBYTES);
        prep_k<<<1842, blk, 0, stream>>>(ft, w1p, w2p, w3p, y1a, y1b, y2a, y2b);
        conv0ab_k<<<grid, blk, 0, stream>>>(x, ftL0, b1p, (void*)y1a, (void*)y1b);
        conv1ab_k<<<grid8, blk, 0, stream>>>(y1a, y1b, f2b0, f2b1, b2p,
                                             (void*)y2a, (void*)y2b);
        conv2ab_k<<<grid, blk, 0, stream>>>(y2a, y2b, f3b0, f3b1, b3p, out);
    } else if (ws_size >= 172032 + 3 * YBYTES) {
        // R23 merged path (5 conv dispatches), alias y2b = y1a (safe:
        // separate dispatches order L1a before L1b).
        u16* y2b = y1a;
        prep_k<<<1842, blk, 0, stream>>>(ft, w1p, w2p, w3p, y1a, y1b, y2a, y2a);
        conv0ab_k<<<grid, blk, 0, stream>>>(x, ftL0, b1p, (void*)y1a, (void*)y1b);
        conv_k<1, false><<<grid, blk, 0, stream>>>(y1a, f2b0, b2p, (void*)y2a);
        conv_k<1, false><<<grid, blk, 0, stream>>>(y1b, f2b1, b2p, (void*)y2b);
        conv2ab_k<<<grid, blk, 0, stream>>>(y2a, y2b, f3b0, f3b1, b3p, out);
    } else {
        // Fallback: exact R22 path (2 buffers: y1a, y1b-as-y2).
        u16* y1 = y1a;
        u16* y2 = y1b;
        prep_k<<<1842, blk, 0, stream>>>(ft, w1p, w2p, w3p, y1, y2, y2, y2);
        for (int br = 0; br < 2; ++br) {
            const u32* f2 = (br == 0) ? f2b0 : f2b1;
            const u32* f3 = (br == 0) ? f3b0 : f3b1;
            conv0_k<<<grid, blk, 0, stream>>>(x, ftL0 + br * 192, b1p, (void*)y1);
            conv_k<1, false><<<grid, blk, 0, stream>>>(y1, f2, b2p, (void*)y2);
            if (br == 0)
                conv_k<2, false><<<grid, blk, 0, stream>>>(y2, f3, b3p, (void*)out);
            else
                conv_k<2, true><<<grid, blk, 0, stream>>>(y2, f3, b3p, (void*)out);
        }
    }
}